// Round 1
// baseline (351.586 us; speedup 1.0000x reference)
//
#include <hip/hip_runtime.h>
#include <hip/hip_fp16.h>

// Problem constants (match reference setup_inputs()).
#define N_NODES 20000
#define E_EDGES 640000
// Layer dims: IN=256, H=8, HF=64, OUT=32

using half8_t = __attribute__((ext_vector_type(8))) _Float16;
using f32x4   = __attribute__((ext_vector_type(4))) float;

__device__ __forceinline__ void fma8(float acc[8], float w, const uint4& v) {
    const _Float16* hv = (const _Float16*)&v;
    #pragma unroll
    for (int c = 0; c < 8; ++c) acc[c] += w * (float)hv[c];
}

// ---------------------------------------------------------------------------
// CSR build: deg init (self-loop counts as 1), count, scan, scatter
// ---------------------------------------------------------------------------
__global__ __launch_bounds__(256) void init_deg_kernel(int* __restrict__ deg, int n) {
    int i = blockIdx.x * 256 + threadIdx.x;
    if (i < n) deg[i] = 1;
}

__global__ __launch_bounds__(256) void count_deg_kernel(const int* __restrict__ ei, int e,
                                                        int* __restrict__ deg) {
    int i = blockIdx.x * 256 + threadIdx.x;
    if (i < e) atomicAdd(&deg[ei[e + i]], 1);  // ei[1][i] = dst
}

// 1024 threads, each owns 20 contiguous elems (covers 20480 >= n).
__global__ __launch_bounds__(1024) void scan_kernel(const int* __restrict__ deg,
                                                    int* __restrict__ row_start,
                                                    int* __restrict__ cursor,
                                                    int n, int total) {
    constexpr int PT = 20;
    __shared__ int wtot[16];
    const int t = threadIdx.x;
    const int lane = t & 63;
    const int wv = t >> 6;
    const int base = t * PT;
    int loc[PT];
    int s = 0;
    #pragma unroll
    for (int i = 0; i < PT; ++i) {
        int idx = base + i;
        int v = (idx < n) ? deg[idx] : 0;
        loc[i] = s;
        s += v;
    }
    int x = s;
    #pragma unroll
    for (int off = 1; off < 64; off <<= 1) {
        int y = __shfl_up(x, off, 64);
        if (lane >= off) x += y;
    }
    if (lane == 63) wtot[wv] = x;
    __syncthreads();
    if (t < 16) {
        int w0 = wtot[t];
        int xx = w0;
        #pragma unroll
        for (int off = 1; off < 16; off <<= 1) {
            int y = __shfl_up(xx, off, 16);
            if (t >= off) xx += y;
        }
        wtot[t] = xx - w0;  // exclusive wave offset
    }
    __syncthreads();
    const int tstart = wtot[wv] + (x - s);
    #pragma unroll
    for (int i = 0; i < PT; ++i) {
        int idx = base + i;
        if (idx < n) {
            int v = tstart + loc[i];
            row_start[idx] = v;
            cursor[idx] = v;
        }
    }
    if (t == 0) row_start[n] = total;
}

__global__ __launch_bounds__(256) void scatter_kernel(const int* __restrict__ ei, int e, int n,
                                                      int* __restrict__ cursor,
                                                      int* __restrict__ csr_src,
                                                      int* __restrict__ csr_dst) {
    int i = blockIdx.x * 256 + threadIdx.x;
    if (i >= e + n) return;
    int s, d;
    if (i < e) { s = ei[i]; d = ei[e + i]; }
    else       { s = i - e; d = s; }       // self-loop
    int slot = atomicAdd(&cursor[d], 1);
    csr_src[slot] = s;
    csr_dst[slot] = d;
}

// ---------------------------------------------------------------------------
// Weight prep: W1t fp16 [512][256] (transposed), W2f fp16 [32][512] with
// W2f[c][h*64+k] = W2[k][h*32+c], and uv[16][64] f32:
//   uv[h][k]   = sum_c W2[k][h*32+c]*att_src2[h][c]   (rows 0..7)
//   uv[8+h][k] = sum_c W2[k][h*32+c]*att_dst2[h][c]   (rows 8..15)
// ---------------------------------------------------------------------------
__global__ __launch_bounds__(256) void prep_kernel(const float* __restrict__ W1,
                                                   const float* __restrict__ W2,
                                                   const float* __restrict__ as2,
                                                   const float* __restrict__ ad2,
                                                   __half* __restrict__ W1t,
                                                   __half* __restrict__ W2f,
                                                   float* __restrict__ uv) {
    int idx = blockIdx.x * 256 + threadIdx.x;
    if (idx < 131072) {
        int n = idx >> 8, k = idx & 255;
        W1t[idx] = __float2half(W1[(size_t)k * 512 + n]);
    } else if (idx < 147456) {
        int t = idx - 131072;
        int hk = t & 511;
        int c = t >> 9, h = hk >> 6, kk = hk & 63;
        W2f[t] = __float2half(W2[(size_t)kk * 256 + h * 32 + c]);
    } else if (idx < 148480) {
        int t = idx - 147456;
        int which = t >> 9;          // 0 = src, 1 = dst
        int hh = (t & 511) >> 6, kk = t & 63;
        const float* a = which ? ad2 : as2;
        float s = 0.f;
        #pragma unroll
        for (int c = 0; c < 32; ++c)
            s += W2[(size_t)kk * 256 + hh * 32 + c] * a[hh * 32 + c];
        uv[t] = s;
    }
}

// x fp32 -> fp16, 8 elems/thread
__global__ __launch_bounds__(256) void cast_kernel(const float* __restrict__ x,
                                                   __half* __restrict__ xh, int total8) {
    int t = blockIdx.x * 256 + threadIdx.x;
    if (t >= total8) return;
    float4 a = *(const float4*)&x[(size_t)t * 8];
    float4 b = *(const float4*)&x[(size_t)t * 8 + 4];
    union { __half h[8]; uint4 u; } pk;
    pk.h[0] = __float2half(a.x); pk.h[1] = __float2half(a.y);
    pk.h[2] = __float2half(a.z); pk.h[3] = __float2half(a.w);
    pk.h[4] = __float2half(b.x); pk.h[5] = __float2half(b.y);
    pk.h[6] = __float2half(b.z); pk.h[7] = __float2half(b.w);
    *(uint4*)&xh[(size_t)t * 8] = pk.u;
}

// ---------------------------------------------------------------------------
// Layer-1 GEMM: A fp16 [M][256], Bt fp16 [512][256] (pre-transposed W1),
// C fp16 [M][512], fused per-head attention logits (CH=64, 2 heads/block).
// 128x128 tile, k-step 32, 4 waves; staging = pure uint4 copies.
// ---------------------------------------------------------------------------
__global__ __launch_bounds__(256) void gemm1_kernel(const __half* __restrict__ A,
                                                    const __half* __restrict__ Bt,
                                                    __half* __restrict__ C,
                                                    const float* __restrict__ att_src,
                                                    const float* __restrict__ att_dst,
                                                    float* __restrict__ asrc_o,
                                                    float* __restrict__ adst_o,
                                                    int M) {
    constexpr int K = 256, N = 512, LD = 40;
    __shared__ __align__(16) _Float16 As[128 * LD];
    __shared__ __align__(16) _Float16 Bs[128 * LD];
    const int tid = threadIdx.x;
    const int bm = blockIdx.x * 128;
    const int bn = blockIdx.y * 128;
    const int w = tid >> 6;
    const int lane = tid & 63;
    const int l16 = lane & 15;
    const int quad = lane >> 4;

    f32x4 acc[2][8];
    #pragma unroll
    for (int r = 0; r < 2; ++r)
        #pragma unroll
        for (int c = 0; c < 8; ++c) acc[r][c] = (f32x4){0.f, 0.f, 0.f, 0.f};

    const int a_r = tid >> 2;          // 64 rows per pass
    const int a_k8 = (tid & 3) * 8;
    for (int k0 = 0; k0 < K; k0 += 32) {
        #pragma unroll
        for (int rr = 0; rr < 2; ++rr) {
            const int row = a_r + rr * 64;
            const int gr = bm + row;
            uint4 av = make_uint4(0, 0, 0, 0);
            if (gr < M) av = *(const uint4*)&A[(size_t)gr * K + k0 + a_k8];
            *(uint4*)&As[row * LD + a_k8] = av;
            uint4 bv = *(const uint4*)&Bt[(size_t)(bn + row) * K + k0 + a_k8];
            *(uint4*)&Bs[row * LD + a_k8] = bv;
        }
        __syncthreads();
        const half8_t af0 = *(const half8_t*)&As[(w * 32 + l16) * LD + quad * 8];
        const half8_t af1 = *(const half8_t*)&As[(w * 32 + 16 + l16) * LD + quad * 8];
        #pragma unroll
        for (int c = 0; c < 8; ++c) {
            const half8_t bf = *(const half8_t*)&Bs[(c * 16 + l16) * LD + quad * 8];
            acc[0][c] = __builtin_amdgcn_mfma_f32_16x16x32_f16(af0, bf, acc[0][c], 0, 0, 0);
            acc[1][c] = __builtin_amdgcn_mfma_f32_16x16x32_f16(af1, bf, acc[1][c], 0, 0, 0);
        }
        __syncthreads();
    }

    // ---- C store (fp16) ----
    #pragma unroll
    for (int rf = 0; rf < 2; ++rf) {
        #pragma unroll
        for (int c = 0; c < 8; ++c) {
            #pragma unroll
            for (int r = 0; r < 4; ++r) {
                int row = bm + w * 32 + rf * 16 + quad * 4 + r;
                if (row < M)
                    C[(size_t)row * N + bn + c * 16 + l16] = __float2half(acc[rf][c][r]);
            }
        }
    }

    // ---- fused logits: block covers 2 full heads (CH=64) ----
    constexpr int HPB = 2, FPH = 4;
    const int hb0 = blockIdx.y * HPB;
    #pragma unroll
    for (int g = 0; g < HPB; ++g) {
        #pragma unroll
        for (int rf = 0; rf < 2; ++rf) {
            float ps[4] = {0.f, 0.f, 0.f, 0.f}, pd[4] = {0.f, 0.f, 0.f, 0.f};
            #pragma unroll
            for (int cc = 0; cc < FPH; ++cc) {
                const int c = g * FPH + cc;
                float av = att_src[(hb0 + g) * 64 + cc * 16 + l16];
                float dv = att_dst[(hb0 + g) * 64 + cc * 16 + l16];
                #pragma unroll
                for (int r = 0; r < 4; ++r) {
                    ps[r] += acc[rf][c][r] * av;
                    pd[r] += acc[rf][c][r] * dv;
                }
            }
            #pragma unroll
            for (int r = 0; r < 4; ++r) {
                #pragma unroll
                for (int off = 8; off; off >>= 1) {
                    ps[r] += __shfl_down(ps[r], off, 16);
                    pd[r] += __shfl_down(pd[r], off, 16);
                }
            }
            if (l16 == 0) {
                #pragma unroll
                for (int r = 0; r < 4; ++r) {
                    int row = bm + w * 32 + rf * 16 + quad * 4 + r;
                    if (row < M) {
                        asrc_o[row * 8 + hb0 + g] = ps[r];
                        adst_o[row * 8 + hb0 + g] = pd[r];
                    }
                }
            }
        }
    }
}

// ---------------------------------------------------------------------------
// Aggregation L1 (CH=64): 4 independent waves/block, wave = 8 dsts x 1 head,
// blockIdx = gg*8 + head for XCD locality; 2-stage pipelined gather.
// s_oe is strictly per-wave -> no block barrier needed (same-wave LDS ops
// are pipe-ordered; removing __syncthreads decouples imbalanced waves).
// ---------------------------------------------------------------------------
__global__ __launch_bounds__(256) void aggregate1_kernel(const __half* __restrict__ h,
                                                         const float* __restrict__ asrc,
                                                         const float* __restrict__ adst,
                                                         const int* __restrict__ row_start,
                                                         const int* __restrict__ csr_src,
                                                         __half* __restrict__ partial) {
    constexpr int MAXD = 64;
    constexpr int LDE = 66;
    __shared__ __align__(16) uint2 s_oe[4][8 * LDE];  // 16896 B
    const int head = blockIdx.x & 7;
    const int gg = blockIdx.x >> 3;
    const int wv = threadIdx.x >> 6;
    const int lane = threadIdx.x & 63;
    const int d = lane >> 3;
    const int il = lane & 7;
    const int i = (gg * 4 + wv) * 8 + d;
    const int start = row_start[i];
    const int deg = row_start[i + 1] - start;
    const float ad = adst[i * 8 + head];
    const bool fast = (deg <= MAXD);

    float lsum = 0.f;
    for (int k = il; k < deg; k += 8) {
        int j = csr_src[start + k];
        float e = asrc[j * 8 + head] + ad;
        e = e > 0.f ? e : 0.2f * e;
        float ex = __expf(e);
        if (fast)
            s_oe[wv][d * LDE + k] = make_uint2((unsigned)(j * 1024), __float_as_uint(ex));
        lsum += ex;
    }
    lsum += __shfl_xor(lsum, 1, 64);
    lsum += __shfl_xor(lsum, 2, 64);
    lsum += __shfl_xor(lsum, 4, 64);
    const float dinv = 1.0f / lsum;

    const int c0 = il * 8;
    const char* __restrict__ hb = (const char*)h + (head * 64 + c0) * 2;
    float acc[8];
    #pragma unroll
    for (int c = 0; c < 8; ++c) acc[c] = 0.f;

    if (fast) {
        const uint2* __restrict__ row = &s_oe[wv][d * LDE];
        int k = 0;
        if (deg >= 8) {
            uint4 q0 = *(const uint4*)&row[0];
            uint4 q1 = *(const uint4*)&row[2];
            uint4 v0 = *(const uint4*)(hb + q0.x);
            uint4 v1 = *(const uint4*)(hb + q0.z);
            uint4 v2 = *(const uint4*)(hb + q1.x);
            uint4 v3 = *(const uint4*)(hb + q1.z);
            for (k = 4; k + 3 < deg; k += 4) {
                uint4 nq0 = *(const uint4*)&row[k];
                uint4 nq1 = *(const uint4*)&row[k + 2];
                uint4 nv0 = *(const uint4*)(hb + nq0.x);
                uint4 nv1 = *(const uint4*)(hb + nq0.z);
                uint4 nv2 = *(const uint4*)(hb + nq1.x);
                uint4 nv3 = *(const uint4*)(hb + nq1.z);
                fma8(acc, __uint_as_float(q0.y), v0);
                fma8(acc, __uint_as_float(q0.w), v1);
                fma8(acc, __uint_as_float(q1.y), v2);
                fma8(acc, __uint_as_float(q1.w), v3);
                q0 = nq0; q1 = nq1; v0 = nv0; v1 = nv1; v2 = nv2; v3 = nv3;
            }
            fma8(acc, __uint_as_float(q0.y), v0);
            fma8(acc, __uint_as_float(q0.w), v1);
            fma8(acc, __uint_as_float(q1.y), v2);
            fma8(acc, __uint_as_float(q1.w), v3);
        }
        for (; k < deg; ++k) {
            uint2 oe = row[k];
            uint4 v = *(const uint4*)(hb + oe.x);
            fma8(acc, __uint_as_float(oe.y), v);
        }
    } else {
        for (int k = 0; k < deg; ++k) {
            int j = csr_src[start + k];
            float e = asrc[j * 8 + head] + ad;
            e = e > 0.f ? e : 0.2f * e;
            uint4 v = *(const uint4*)(hb + (size_t)j * 1024);
            fma8(acc, __expf(e), v);
        }
    }

    union { __half h8[8]; uint4 u4; } pk;
    #pragma unroll
    for (int c = 0; c < 8; ++c) pk.h8[c] = __float2half(acc[c] * dinv);
    *(uint4*)&partial[((size_t)i * 8 + head) * 64 + c0] = pk.u4;
}

// ---------------------------------------------------------------------------
// Merge heads layer 1: y1 = relu(mean_h partial + b1), fp16 out.
// ---------------------------------------------------------------------------
__global__ __launch_bounds__(256) void merge1_kernel(const __half* __restrict__ partial,
                                                     const float* __restrict__ bias,
                                                     __half* __restrict__ out) {
    int flat = blockIdx.x * 256 + threadIdx.x;
    int i = flat >> 6;
    int c = flat & 63;
    float s = 0.f;
    #pragma unroll
    for (int h8 = 0; h8 < 8; ++h8)
        s += __half2float(partial[((size_t)i * 8 + h8) * 64 + c]);
    s = s * 0.125f + bias[c];
    s = fmaxf(s, 0.f);
    out[flat] = __float2half(s);
}

// ---------------------------------------------------------------------------
// Layer-2 logits from y1 directly: asrc2[i,h] = y1_i . uv[h], adst2[i,h] =
// y1_i . uv[8+h].  Wave = 4 nodes x 16 targets.
// ---------------------------------------------------------------------------
__global__ __launch_bounds__(256) void logits2_kernel(const __half* __restrict__ y1,
                                                      const float* __restrict__ uv,
                                                      float* __restrict__ asrc2,
                                                      float* __restrict__ adst2) {
    const int tid = threadIdx.x;
    const int wv = tid >> 6, lane = tid & 63;
    const int d = lane >> 4, t = lane & 15;
    const int i = blockIdx.x * 16 + wv * 4 + d;
    const float* uvr = uv + t * 64;
    float s = 0.f;
    #pragma unroll
    for (int c0 = 0; c0 < 64; c0 += 8) {
        uint4 yq = *(const uint4*)&y1[(size_t)i * 64 + c0];
        const _Float16* yh = (const _Float16*)&yq;
        float4 u0 = *(const float4*)&uvr[c0];
        float4 u1 = *(const float4*)&uvr[c0 + 4];
        s += (float)yh[0] * u0.x + (float)yh[1] * u0.y + (float)yh[2] * u0.z +
             (float)yh[3] * u0.w + (float)yh[4] * u1.x + (float)yh[5] * u1.y +
             (float)yh[6] * u1.z + (float)yh[7] * u1.w;
    }
    if (t < 8) asrc2[i * 8 + t] = s;
    else       adst2[i * 8 + (t - 8)] = s;
}

// ---------------------------------------------------------------------------
// Per-edge exponentials for layer 2 (all 8 heads packed fp16, 16B/edge).
// ---------------------------------------------------------------------------
__global__ __launch_bounds__(256) void exp_kernel(const int* __restrict__ csr_src,
                                                  const int* __restrict__ csr_dst,
                                                  const float* __restrict__ asrc2,
                                                  const float* __restrict__ adst2,
                                                  __half* __restrict__ exps, int total) {
    int s = blockIdx.x * 256 + threadIdx.x;
    if (s >= total) return;
    int j = csr_src[s], i = csr_dst[s];
    float4 a0 = *(const float4*)&asrc2[(size_t)j * 8];
    float4 a1 = *(const float4*)&asrc2[(size_t)j * 8 + 4];
    float4 d0 = *(const float4*)&adst2[(size_t)i * 8];
    float4 d1 = *(const float4*)&adst2[(size_t)i * 8 + 4];
    float e[8] = {a0.x + d0.x, a0.y + d0.y, a0.z + d0.z, a0.w + d0.w,
                  a1.x + d1.x, a1.y + d1.y, a1.z + d1.z, a1.w + d1.w};
    union { __half h[8]; uint4 u; } pk;
    #pragma unroll
    for (int h = 0; h < 8; ++h) {
        float ee = e[h] > 0.f ? e[h] : 0.2f * e[h];
        pk.h[h] = __float2half(__expf(ee));
    }
    *(uint4*)&exps[(size_t)s * 8] = pk.u;
}

// ---------------------------------------------------------------------------
// Aggregation L2 in y1-space: S[i,h,:] = (sum_j ex_jh * y1_j) / den_ih.
// Gather is y1 (2.56 MB, L2-resident) at 128 B/edge -- 4x less traffic than
// aggregating in h2-space.  Wave = 2 dsts x 32 lanes (2 channels/lane),
// acc[8][2] f32; exps streamed 16B/edge; csr_src streamed via uint4.
// ---------------------------------------------------------------------------
__global__ __launch_bounds__(256) void aggregate2_kernel(const __half* __restrict__ y1,
                                                         const __half* __restrict__ exps,
                                                         const int* __restrict__ row_start,
                                                         const int* __restrict__ csr_src,
                                                         __half* __restrict__ S) {
    const int tid = threadIdx.x;
    const int wv = tid >> 6, lane = tid & 63;
    const int d = lane >> 5, il = lane & 31;
    const int i = blockIdx.x * 8 + wv * 2 + d;
    const int start = row_start[i];
    const int deg = row_start[i + 1] - start;
    const int myh = il & 7;

    float acc[8][2];
    #pragma unroll
    for (int h = 0; h < 8; ++h) { acc[h][0] = 0.f; acc[h][1] = 0.f; }
    float den = 0.f;

    auto step = [&](int j, int k) {
        uint4 exq = *(const uint4*)&exps[(size_t)(start + k) * 8];
        unsigned yp = *(const unsigned*)&y1[(size_t)j * 64 + il * 2];
        const _Float16* ex = (const _Float16*)&exq;
        const _Float16* yv = (const _Float16*)&yp;
        float y0 = (float)yv[0], y1f = (float)yv[1];
        #pragma unroll
        for (int h = 0; h < 8; ++h) {
            float ef = (float)ex[h];
            acc[h][0] += ef * y0;
            acc[h][1] += ef * y1f;
        }
        unsigned word = (myh & 4) ? ((myh & 2) ? exq.w : exq.z)
                                  : ((myh & 2) ? exq.y : exq.x);
        unsigned hb = (word >> ((myh & 1) * 16)) & 0xffffu;
        union { unsigned short u; __half hh; } cv;
        cv.u = (unsigned short)hb;
        den += __half2float(cv.hh);
    };

    int k = 0;
    uint4 jq = *(const uint4*)&csr_src[start];  // deg>=1 (self-loop); array padded
    for (; k + 4 <= deg; k += 4) {
        uint4 jn = *(const uint4*)&csr_src[start + k + 4];
        step(jq.x, k); step(jq.y, k + 1); step(jq.z, k + 2); step(jq.w, k + 3);
        jq = jn;
    }
    if (k < deg) { step(jq.x, k); ++k; }
    if (k < deg) { step(jq.y, k); ++k; }
    if (k < deg) { step(jq.z, k); ++k; }

    float dinv[8];
    #pragma unroll
    for (int h = 0; h < 8; ++h) {
        float dh = __shfl(den, (lane & 32) + h, 64);
        dinv[h] = 1.0f / dh;
    }
    #pragma unroll
    for (int h = 0; h < 8; ++h) {
        __half2 p;
        p.x = __float2half(acc[h][0] * dinv[h]);
        p.y = __float2half(acc[h][1] * dinv[h]);
        *(__half2*)&S[(size_t)i * 512 + h * 64 + il * 2] = p;
    }
}

// ---------------------------------------------------------------------------
// Final GEMM: out = S[M][512] @ W2f^T (W2f fp16 [32][512]) * 1/8 + b2, fp32.
// 128x32 tile, k-step 32, 4 waves (wave = 32 rows x 32 cols).
// ---------------------------------------------------------------------------
__global__ __launch_bounds__(256) void gemm_out_kernel(const __half* __restrict__ A,
                                                       const __half* __restrict__ Bt,
                                                       const float* __restrict__ bias,
                                                       float* __restrict__ out, int M) {
    constexpr int K = 512, LD = 40;
    __shared__ __align__(16) _Float16 As[128 * LD];
    __shared__ __align__(16) _Float16 Bs[32 * LD];
    const int tid = threadIdx.x;
    const int bm = blockIdx.x * 128;
    const int w = tid >> 6, lane = tid & 63;
    const int l16 = lane & 15, quad = lane >> 4;
    f32x4 acc[2][2];
    #pragma unroll
    for (int r = 0; r < 2; ++r)
        #pragma unroll
        for (int c = 0; c < 2; ++c) acc[r][c] = (f32x4){0.f, 0.f, 0.f, 0.f};

    const int a_r = tid >> 2, a_k8 = (tid & 3) * 8;
    for (int k0 = 0; k0 < K; k0 += 32) {
        #pragma unroll
        for (int rr = 0; rr < 2; ++rr) {
            const int row = a_r + rr * 64;
            const int gr = bm + row;
            uint4 av = make_uint4(0, 0, 0, 0);
            if (gr < M) av = *(const uint4*)&A[(size_t)gr * K + k0 + a_k8];
            *(uint4*)&As[row * LD + a_k8] = av;
        }
        if (tid < 128) {
            const int nr = tid >> 2, k8 = (tid & 3) * 8;
            *(uint4*)&Bs[nr * LD + k8] = *(const uint4*)&Bt[(size_t)nr * K + k0 + k8];
        }
        __syncthreads();
        const half8_t af0 = *(const half8_t*)&As[(w * 32 + l16) * LD + quad * 8];
        const half8_t af1 = *(const half8_t*)&As[(w * 32 + 16 + l16) * LD + quad * 8];
        #pragma unroll
        for (int c = 0; c < 2; ++c) {
            const half8_t bf = *(const half8_t*)&Bs[(c * 16 + l16) * LD + quad * 8];
            acc[0][c] = __builtin_amdgcn_mfma_f32_16x16x32_f16(af0, bf, acc[0][c], 0, 0, 0);
            acc[1][c] = __builtin_amdgcn_mfma_f32_16x16x32_f16(af1, bf, acc[1][c], 0, 0, 0);
        }
        __syncthreads();
    }
    #pragma unroll
    for (int rf = 0; rf < 2; ++rf) {
        #pragma unroll
        for (int c = 0; c < 2; ++c) {
            #pragma unroll
            for (int r = 0; r < 4; ++r) {
                int row = bm + w * 32 + rf * 16 + quad * 4 + r;
                if (row < M)
                    out[(size_t)row * 32 + c * 16 + l16] =
                        acc[rf][c][r] * 0.125f + bias[c * 16 + l16];
            }
        }
    }
}

// ---------------------------------------------------------------------------
// Launch
// ---------------------------------------------------------------------------
extern "C" void kernel_launch(void* const* d_in, const int* in_sizes, int n_in,
                              void* d_out, int out_size, void* d_ws, size_t ws_size,
                              hipStream_t stream) {
    const float* x   = (const float*)d_in[0];
    const int*   ei  = (const int*)d_in[1];
    const float* W1  = (const float*)d_in[2];
    const float* as1 = (const float*)d_in[3];
    const float* ad1 = (const float*)d_in[4];
    const float* b1  = (const float*)d_in[5];
    const float* W2  = (const float*)d_in[6];
    const float* as2 = (const float*)d_in[7];
    const float* ad2 = (const float*)d_in[8];
    const float* b2  = (const float*)d_in[9];

    const int n = N_NODES;
    const int e = E_EDGES;

    // ---- workspace layout (with lifetime-based aliasing) ----
    char* w = (char*)d_ws;
    __half* partial = (__half*)w; w += (size_t)n * 8 * 64 * 2;  // 20.48 MB
    __half* h_buf   = (__half*)w; w += (size_t)n * 512 * 2;     // 20.48 MB
    __half* y1h     = (__half*)w; w += (size_t)n * 64 * 2;      //  2.56 MB
    __half* W1t     = (__half*)w; w += (size_t)512 * 256 * 2;
    __half* W2f     = (__half*)w; w += (size_t)32 * 512 * 2;
    float*  uv      = (float*)w;  w += (size_t)16 * 64 * 4;
    float*  asrc    = (float*)w;  w += (size_t)n * 8 * 4;
    float*  adst    = (float*)w;  w += (size_t)n * 8 * 4;
    int* deg        = (int*)w; w += (size_t)n * 4;
    int* row_start  = (int*)w; w += (size_t)(n + 1) * 4;
    int* cursor     = (int*)w; w += (size_t)n * 4;
    int* csr_src    = (int*)w; w += (size_t)(e + n + 8) * 4;   // +pad for uint4 reads
    int* csr_dst    = (int*)w; w += (size_t)(e + n) * 4;
    // aliases (sequential lifetimes):
    __half* xh    = partial;   // x fp16 [n][256]: dead once gemm1 done, before agg1 writes partial
    __half* exps  = partial;   // [e+n][8] fp16: written after merge1 (last partial read)
    __half* S     = h_buf;     // [n][512] fp16: written after agg1 (last h_buf read)
    float* asrc2  = asrc;      // reused after agg1 (last asrc/adst read)
    float* adst2  = adst;

    // ---- CSR build (graph identical for both layers) ----
    init_deg_kernel<<<(n + 255) / 256, 256, 0, stream>>>(deg, n);
    count_deg_kernel<<<(e + 255) / 256, 256, 0, stream>>>(ei, e, deg);
    scan_kernel<<<1, 1024, 0, stream>>>(deg, row_start, cursor, n, e + n);
    scatter_kernel<<<(e + n + 255) / 256, 256, 0, stream>>>(ei, e, n, cursor, csr_src, csr_dst);

    // ---- weight prep + x cast ----
    prep_kernel<<<(148480 + 255) / 256, 256, 0, stream>>>(W1, W2, as2, ad2, W1t, W2f, uv);
    cast_kernel<<<(n * 256 / 8 + 255) / 256, 256, 0, stream>>>(x, xh, n * 256 / 8);

    const int mb = (n + 127) / 128;  // 157

    // ---- Layer 1 ----
    gemm1_kernel<<<dim3(mb, 4), 256, 0, stream>>>(xh, W1t, h_buf, as1, ad1, asrc, adst, n);
    aggregate1_kernel<<<(n / 32) * 8, 256, 0, stream>>>(h_buf, asrc, adst, row_start,
                                                        csr_src, partial);
    merge1_kernel<<<n * 64 / 256, 256, 0, stream>>>(partial, b1, y1h);

    // ---- Layer 2: aggregate in y1-space, then one small GEMM ----
    logits2_kernel<<<n / 16, 256, 0, stream>>>(y1h, uv, asrc2, adst2);
    exp_kernel<<<(e + n + 255) / 256, 256, 0, stream>>>(csr_src, csr_dst, asrc2, adst2,
                                                        exps, e + n);
    aggregate2_kernel<<<n / 8, 256, 0, stream>>>(y1h, exps, row_start, csr_src, S);
    gemm_out_kernel<<<mb, 256, 0, stream>>>(S, W2f, b2, (float*)d_out, n);
}

// Round 2
// 332.939 us; speedup vs baseline: 1.0560x; 1.0560x over previous
//
#include <hip/hip_runtime.h>
#include <hip/hip_fp16.h>

// Problem constants (match reference setup_inputs()).
#define N_NODES 20000
#define E_EDGES 640000
// Layer dims: IN=256, H=8, HF=64, OUT=32

using half8_t = __attribute__((ext_vector_type(8))) _Float16;
using f32x4   = __attribute__((ext_vector_type(4))) float;

__device__ __forceinline__ void fma8(float acc[8], float w, const uint4& v) {
    const _Float16* hv = (const _Float16*)&v;
    #pragma unroll
    for (int c = 0; c < 8; ++c) acc[c] += w * (float)hv[c];
}

// ---------------------------------------------------------------------------
// CSR build: deg init (self-loop counts as 1), count, scan, scatter
// ---------------------------------------------------------------------------
__global__ __launch_bounds__(256) void init_deg_kernel(int* __restrict__ deg, int n) {
    int i = blockIdx.x * 256 + threadIdx.x;
    if (i < n) deg[i] = 1;
}

__global__ __launch_bounds__(256) void count_deg_kernel(const int* __restrict__ ei, int e,
                                                        int* __restrict__ deg) {
    int i = blockIdx.x * 256 + threadIdx.x;
    if (i < e) atomicAdd(&deg[ei[e + i]], 1);  // ei[1][i] = dst
}

// 1024 threads, each owns 20 contiguous elems (covers 20480 >= n).
__global__ __launch_bounds__(1024) void scan_kernel(const int* __restrict__ deg,
                                                    int* __restrict__ row_start,
                                                    int* __restrict__ cursor,
                                                    int n, int total) {
    constexpr int PT = 20;
    __shared__ int wtot[16];
    const int t = threadIdx.x;
    const int lane = t & 63;
    const int wv = t >> 6;
    const int base = t * PT;
    int loc[PT];
    int s = 0;
    #pragma unroll
    for (int i = 0; i < PT; ++i) {
        int idx = base + i;
        int v = (idx < n) ? deg[idx] : 0;
        loc[i] = s;
        s += v;
    }
    int x = s;
    #pragma unroll
    for (int off = 1; off < 64; off <<= 1) {
        int y = __shfl_up(x, off, 64);
        if (lane >= off) x += y;
    }
    if (lane == 63) wtot[wv] = x;
    __syncthreads();
    if (t < 16) {
        int w0 = wtot[t];
        int xx = w0;
        #pragma unroll
        for (int off = 1; off < 16; off <<= 1) {
            int y = __shfl_up(xx, off, 16);
            if (t >= off) xx += y;
        }
        wtot[t] = xx - w0;  // exclusive wave offset
    }
    __syncthreads();
    const int tstart = wtot[wv] + (x - s);
    #pragma unroll
    for (int i = 0; i < PT; ++i) {
        int idx = base + i;
        if (idx < n) {
            int v = tstart + loc[i];
            row_start[idx] = v;
            cursor[idx] = v;
        }
    }
    if (t == 0) row_start[n] = total;
}

__global__ __launch_bounds__(256) void scatter_kernel(const int* __restrict__ ei, int e, int n,
                                                      int* __restrict__ cursor,
                                                      int* __restrict__ csr_src) {
    int i = blockIdx.x * 256 + threadIdx.x;
    if (i >= e + n) return;
    int s, d;
    if (i < e) { s = ei[i]; d = ei[e + i]; }
    else       { s = i - e; d = s; }       // self-loop
    int slot = atomicAdd(&cursor[d], 1);
    csr_src[slot] = s;
}

// ---------------------------------------------------------------------------
// Fused prep: x cast (fp32->fp16, idx<640000, 8 elems/thread) + weight prep.
// W1t fp16 [512][256] (transposed), W2f fp16 [32][512] with
// W2f[c][h*64+k] = W2[k][h*32+c], and uv[16][64] f32:
//   uv[h][k]   = sum_c W2[k][h*32+c]*att_src2[h][c]   (rows 0..7)
//   uv[8+h][k] = sum_c W2[k][h*32+c]*att_dst2[h][c]   (rows 8..15)
// ---------------------------------------------------------------------------
__global__ __launch_bounds__(256) void prep_kernel(const float* __restrict__ x,
                                                   __half* __restrict__ xh,
                                                   const float* __restrict__ W1,
                                                   const float* __restrict__ W2,
                                                   const float* __restrict__ as2,
                                                   const float* __restrict__ ad2,
                                                   __half* __restrict__ W1t,
                                                   __half* __restrict__ W2f,
                                                   float* __restrict__ uv) {
    int gidx = blockIdx.x * 256 + threadIdx.x;
    if (gidx < 640000) {  // cast: n*256/8 threads
        int t = gidx;
        float4 a = *(const float4*)&x[(size_t)t * 8];
        float4 b = *(const float4*)&x[(size_t)t * 8 + 4];
        union { __half h[8]; uint4 u; } pk;
        pk.h[0] = __float2half(a.x); pk.h[1] = __float2half(a.y);
        pk.h[2] = __float2half(a.z); pk.h[3] = __float2half(a.w);
        pk.h[4] = __float2half(b.x); pk.h[5] = __float2half(b.y);
        pk.h[6] = __float2half(b.z); pk.h[7] = __float2half(b.w);
        *(uint4*)&xh[(size_t)t * 8] = pk.u;
        return;
    }
    int idx = gidx - 640000;
    if (idx < 131072) {
        int nn = idx >> 8, k = idx & 255;
        W1t[idx] = __float2half(W1[(size_t)k * 512 + nn]);
    } else if (idx < 147456) {
        int t = idx - 131072;
        int hk = t & 511;
        int c = t >> 9, h = hk >> 6, kk = hk & 63;
        W2f[t] = __float2half(W2[(size_t)kk * 256 + h * 32 + c]);
    } else if (idx < 148480) {
        int t = idx - 147456;
        int which = t >> 9;          // 0 = src, 1 = dst
        int hh = (t & 511) >> 6, kk = t & 63;
        const float* a = which ? ad2 : as2;
        float s = 0.f;
        #pragma unroll
        for (int c = 0; c < 32; ++c)
            s += W2[(size_t)kk * 256 + hh * 32 + c] * a[hh * 32 + c];
        uv[t] = s;
    }
}

// ---------------------------------------------------------------------------
// Layer-1 GEMM: A fp16 [M][256], Bt fp16 [512][256] (pre-transposed W1),
// C fp16 [M][512], fused per-head attention logits (CH=64, 2 heads/block).
// 128x128 tile, k-step 32, 4 waves; staging = pure uint4 copies.
// ---------------------------------------------------------------------------
__global__ __launch_bounds__(256) void gemm1_kernel(const __half* __restrict__ A,
                                                    const __half* __restrict__ Bt,
                                                    __half* __restrict__ C,
                                                    const float* __restrict__ att_src,
                                                    const float* __restrict__ att_dst,
                                                    float* __restrict__ asrc_o,
                                                    float* __restrict__ adst_o,
                                                    int M) {
    constexpr int K = 256, N = 512, LD = 40;
    __shared__ __align__(16) _Float16 As[128 * LD];
    __shared__ __align__(16) _Float16 Bs[128 * LD];
    const int tid = threadIdx.x;
    const int bm = blockIdx.x * 128;
    const int bn = blockIdx.y * 128;
    const int w = tid >> 6;
    const int lane = tid & 63;
    const int l16 = lane & 15;
    const int quad = lane >> 4;

    f32x4 acc[2][8];
    #pragma unroll
    for (int r = 0; r < 2; ++r)
        #pragma unroll
        for (int c = 0; c < 8; ++c) acc[r][c] = (f32x4){0.f, 0.f, 0.f, 0.f};

    const int a_r = tid >> 2;          // 64 rows per pass
    const int a_k8 = (tid & 3) * 8;
    for (int k0 = 0; k0 < K; k0 += 32) {
        #pragma unroll
        for (int rr = 0; rr < 2; ++rr) {
            const int row = a_r + rr * 64;
            const int gr = bm + row;
            uint4 av = make_uint4(0, 0, 0, 0);
            if (gr < M) av = *(const uint4*)&A[(size_t)gr * K + k0 + a_k8];
            *(uint4*)&As[row * LD + a_k8] = av;
            uint4 bv = *(const uint4*)&Bt[(size_t)(bn + row) * K + k0 + a_k8];
            *(uint4*)&Bs[row * LD + a_k8] = bv;
        }
        __syncthreads();
        const half8_t af0 = *(const half8_t*)&As[(w * 32 + l16) * LD + quad * 8];
        const half8_t af1 = *(const half8_t*)&As[(w * 32 + 16 + l16) * LD + quad * 8];
        #pragma unroll
        for (int c = 0; c < 8; ++c) {
            const half8_t bf = *(const half8_t*)&Bs[(c * 16 + l16) * LD + quad * 8];
            acc[0][c] = __builtin_amdgcn_mfma_f32_16x16x32_f16(af0, bf, acc[0][c], 0, 0, 0);
            acc[1][c] = __builtin_amdgcn_mfma_f32_16x16x32_f16(af1, bf, acc[1][c], 0, 0, 0);
        }
        __syncthreads();
    }

    // ---- C store (fp16) ----
    #pragma unroll
    for (int rf = 0; rf < 2; ++rf) {
        #pragma unroll
        for (int c = 0; c < 8; ++c) {
            #pragma unroll
            for (int r = 0; r < 4; ++r) {
                int row = bm + w * 32 + rf * 16 + quad * 4 + r;
                if (row < M)
                    C[(size_t)row * N + bn + c * 16 + l16] = __float2half(acc[rf][c][r]);
            }
        }
    }

    // ---- fused logits: block covers 2 full heads (CH=64) ----
    constexpr int HPB = 2, FPH = 4;
    const int hb0 = blockIdx.y * HPB;
    #pragma unroll
    for (int g = 0; g < HPB; ++g) {
        #pragma unroll
        for (int rf = 0; rf < 2; ++rf) {
            float ps[4] = {0.f, 0.f, 0.f, 0.f}, pd[4] = {0.f, 0.f, 0.f, 0.f};
            #pragma unroll
            for (int cc = 0; cc < FPH; ++cc) {
                const int c = g * FPH + cc;
                float av = att_src[(hb0 + g) * 64 + cc * 16 + l16];
                float dv = att_dst[(hb0 + g) * 64 + cc * 16 + l16];
                #pragma unroll
                for (int r = 0; r < 4; ++r) {
                    ps[r] += acc[rf][c][r] * av;
                    pd[r] += acc[rf][c][r] * dv;
                }
            }
            #pragma unroll
            for (int r = 0; r < 4; ++r) {
                #pragma unroll
                for (int off = 8; off; off >>= 1) {
                    ps[r] += __shfl_down(ps[r], off, 16);
                    pd[r] += __shfl_down(pd[r], off, 16);
                }
            }
            if (l16 == 0) {
                #pragma unroll
                for (int r = 0; r < 4; ++r) {
                    int row = bm + w * 32 + rf * 16 + quad * 4 + r;
                    if (row < M) {
                        asrc_o[row * 8 + hb0 + g] = ps[r];
                        adst_o[row * 8 + hb0 + g] = pd[r];
                    }
                }
            }
        }
    }
}

// ---------------------------------------------------------------------------
// Aggregation L1 (CH=64): 4 independent waves/block, wave = 8 dsts x 1 head,
// blockIdx = gg*8 + head for XCD locality; 2-stage pipelined gather.
// (Pinned at ~67 us -> L2 random-gather wall; frozen.)
// ---------------------------------------------------------------------------
__global__ __launch_bounds__(256) void aggregate1_kernel(const __half* __restrict__ h,
                                                         const float* __restrict__ asrc,
                                                         const float* __restrict__ adst,
                                                         const int* __restrict__ row_start,
                                                         const int* __restrict__ csr_src,
                                                         __half* __restrict__ partial) {
    constexpr int MAXD = 64;
    constexpr int LDE = 66;
    __shared__ __align__(16) uint2 s_oe[4][8 * LDE];  // 16896 B
    const int head = blockIdx.x & 7;
    const int gg = blockIdx.x >> 3;
    const int wv = threadIdx.x >> 6;
    const int lane = threadIdx.x & 63;
    const int d = lane >> 3;
    const int il = lane & 7;
    const int i = (gg * 4 + wv) * 8 + d;
    const int start = row_start[i];
    const int deg = row_start[i + 1] - start;
    const float ad = adst[i * 8 + head];
    const bool fast = (deg <= MAXD);

    float lsum = 0.f;
    for (int k = il; k < deg; k += 8) {
        int j = csr_src[start + k];
        float e = asrc[j * 8 + head] + ad;
        e = e > 0.f ? e : 0.2f * e;
        float ex = __expf(e);
        if (fast)
            s_oe[wv][d * LDE + k] = make_uint2((unsigned)(j * 1024), __float_as_uint(ex));
        lsum += ex;
    }
    lsum += __shfl_xor(lsum, 1, 64);
    lsum += __shfl_xor(lsum, 2, 64);
    lsum += __shfl_xor(lsum, 4, 64);
    const float dinv = 1.0f / lsum;

    const int c0 = il * 8;
    const char* __restrict__ hb = (const char*)h + (head * 64 + c0) * 2;
    float acc[8];
    #pragma unroll
    for (int c = 0; c < 8; ++c) acc[c] = 0.f;

    if (fast) {
        const uint2* __restrict__ row = &s_oe[wv][d * LDE];
        int k = 0;
        if (deg >= 8) {
            uint4 q0 = *(const uint4*)&row[0];
            uint4 q1 = *(const uint4*)&row[2];
            uint4 v0 = *(const uint4*)(hb + q0.x);
            uint4 v1 = *(const uint4*)(hb + q0.z);
            uint4 v2 = *(const uint4*)(hb + q1.x);
            uint4 v3 = *(const uint4*)(hb + q1.z);
            for (k = 4; k + 3 < deg; k += 4) {
                uint4 nq0 = *(const uint4*)&row[k];
                uint4 nq1 = *(const uint4*)&row[k + 2];
                uint4 nv0 = *(const uint4*)(hb + nq0.x);
                uint4 nv1 = *(const uint4*)(hb + nq0.z);
                uint4 nv2 = *(const uint4*)(hb + nq1.x);
                uint4 nv3 = *(const uint4*)(hb + nq1.z);
                fma8(acc, __uint_as_float(q0.y), v0);
                fma8(acc, __uint_as_float(q0.w), v1);
                fma8(acc, __uint_as_float(q1.y), v2);
                fma8(acc, __uint_as_float(q1.w), v3);
                q0 = nq0; q1 = nq1; v0 = nv0; v1 = nv1; v2 = nv2; v3 = nv3;
            }
            fma8(acc, __uint_as_float(q0.y), v0);
            fma8(acc, __uint_as_float(q0.w), v1);
            fma8(acc, __uint_as_float(q1.y), v2);
            fma8(acc, __uint_as_float(q1.w), v3);
        }
        for (; k < deg; ++k) {
            uint2 oe = row[k];
            uint4 v = *(const uint4*)(hb + oe.x);
            fma8(acc, __uint_as_float(oe.y), v);
        }
    } else {
        for (int k = 0; k < deg; ++k) {
            int j = csr_src[start + k];
            float e = asrc[j * 8 + head] + ad;
            e = e > 0.f ? e : 0.2f * e;
            uint4 v = *(const uint4*)(hb + (size_t)j * 1024);
            fma8(acc, __expf(e), v);
        }
    }

    union { __half h8[8]; uint4 u4; } pk;
    #pragma unroll
    for (int c = 0; c < 8; ++c) pk.h8[c] = __float2half(acc[c] * dinv);
    *(uint4*)&partial[((size_t)i * 8 + head) * 64 + c0] = pk.u4;
}

// ---------------------------------------------------------------------------
// Merge heads layer 1: y1 = relu(mean_h partial + b1), fp16 out.
// ---------------------------------------------------------------------------
__global__ __launch_bounds__(256) void merge1_kernel(const __half* __restrict__ partial,
                                                     const float* __restrict__ bias,
                                                     __half* __restrict__ out) {
    int flat = blockIdx.x * 256 + threadIdx.x;
    int i = flat >> 6;
    int c = flat & 63;
    float s = 0.f;
    #pragma unroll
    for (int h8 = 0; h8 < 8; ++h8)
        s += __half2float(partial[((size_t)i * 8 + h8) * 64 + c]);
    s = s * 0.125f + bias[c];
    s = fmaxf(s, 0.f);
    out[flat] = __float2half(s);
}

// ---------------------------------------------------------------------------
// Layer-2 logits from y1 directly: asrc2[i,h] = y1_i . uv[h], adst2[i,h] =
// y1_i . uv[8+h].  Wave = 4 nodes x 16 targets.
// ---------------------------------------------------------------------------
__global__ __launch_bounds__(256) void logits2_kernel(const __half* __restrict__ y1,
                                                      const float* __restrict__ uv,
                                                      float* __restrict__ asrc2,
                                                      float* __restrict__ adst2) {
    const int tid = threadIdx.x;
    const int wv = tid >> 6, lane = tid & 63;
    const int d = lane >> 4, t = lane & 15;
    const int i = blockIdx.x * 16 + wv * 4 + d;
    const float* uvr = uv + t * 64;
    float s = 0.f;
    #pragma unroll
    for (int c0 = 0; c0 < 64; c0 += 8) {
        uint4 yq = *(const uint4*)&y1[(size_t)i * 64 + c0];
        const _Float16* yh = (const _Float16*)&yq;
        float4 u0 = *(const float4*)&uvr[c0];
        float4 u1 = *(const float4*)&uvr[c0 + 4];
        s += (float)yh[0] * u0.x + (float)yh[1] * u0.y + (float)yh[2] * u0.z +
             (float)yh[3] * u0.w + (float)yh[4] * u1.x + (float)yh[5] * u1.y +
             (float)yh[6] * u1.z + (float)yh[7] * u1.w;
    }
    if (t < 8) asrc2[i * 8 + t] = s;
    else       adst2[i * 8 + (t - 8)] = s;
}

// ---------------------------------------------------------------------------
// Aggregation L2 in y1-space with fused softmax: wave = 1 dst, lane = (head
// h=lane>>3, channels c8=(lane&7)*8).  Each lane computes its head's exp
// inline (1 expf/edge/lane), den is lane-redundant (no reduction needed).
// Gather: y1 row (128 B, L2-resident 2.56 MB table) + asrc2 word per edge.
// S[i][h*64+c] = (sum_j ex_jh * y1_j[c]) / den_ih, fp16.
// ---------------------------------------------------------------------------
__global__ __launch_bounds__(256) void aggregate2_kernel(const __half* __restrict__ y1,
                                                         const float* __restrict__ asrc2,
                                                         const float* __restrict__ adst2,
                                                         const int* __restrict__ row_start,
                                                         const int* __restrict__ csr_src,
                                                         __half* __restrict__ S) {
    const int tid = threadIdx.x;
    const int wv = tid >> 6, lane = tid & 63;
    const int h = lane >> 3;
    const int c8 = (lane & 7) * 8;
    const int i = blockIdx.x * 4 + wv;
    const int start = row_start[i];
    const int deg = row_start[i + 1] - start;
    const float adh = adst2[i * 8 + h];

    float acc[8];
    #pragma unroll
    for (int c = 0; c < 8; ++c) acc[c] = 0.f;
    float den = 0.f;

    auto step = [&](int j) {
        float e = asrc2[j * 8 + h] + adh;
        e = e > 0.f ? e : 0.2f * e;
        float ex = __expf(e);
        den += ex;
        uint4 yq = *(const uint4*)&y1[(size_t)j * 64 + c8];
        const _Float16* yv = (const _Float16*)&yq;
        #pragma unroll
        for (int c = 0; c < 8; ++c) acc[c] += ex * (float)yv[c];
    };

    int k = 0;
    uint4 jq = *(const uint4*)&csr_src[start];  // deg>=1 (self-loop); array padded
    for (; k + 4 <= deg; k += 4) {
        uint4 jn = *(const uint4*)&csr_src[start + k + 4];
        step(jq.x); step(jq.y); step(jq.z); step(jq.w);
        jq = jn;
    }
    if (k < deg) { step(jq.x); ++k; }
    if (k < deg) { step(jq.y); ++k; }
    if (k < deg) { step(jq.z); ++k; }

    const float dinv = 1.0f / den;
    union { __half h8[8]; uint4 u4; } pk;
    #pragma unroll
    for (int c = 0; c < 8; ++c) pk.h8[c] = __float2half(acc[c] * dinv);
    *(uint4*)&S[(size_t)i * 512 + h * 64 + c8] = pk.u4;
}

// ---------------------------------------------------------------------------
// Final GEMM: out = S[M][512] @ W2f^T (W2f fp16 [32][512]) * 1/8 + b2, fp32.
// 64x32 tile (313 blocks for CU coverage), k-step 32, 4 waves
// (wave = 16 rows x 32 cols, 2 MFMA/k-step).
// ---------------------------------------------------------------------------
__global__ __launch_bounds__(256) void gemm_out_kernel(const __half* __restrict__ A,
                                                       const __half* __restrict__ Bt,
                                                       const float* __restrict__ bias,
                                                       float* __restrict__ out, int M) {
    constexpr int K = 512, LD = 40;
    __shared__ __align__(16) _Float16 As[64 * LD];
    __shared__ __align__(16) _Float16 Bs[32 * LD];
    const int tid = threadIdx.x;
    const int bm = blockIdx.x * 64;
    const int w = tid >> 6, lane = tid & 63;
    const int l16 = lane & 15, quad = lane >> 4;
    f32x4 acc[2];
    #pragma unroll
    for (int c = 0; c < 2; ++c) acc[c] = (f32x4){0.f, 0.f, 0.f, 0.f};

    const int a_r = tid >> 2, a_k8 = (tid & 3) * 8;
    for (int k0 = 0; k0 < K; k0 += 32) {
        const int gr = bm + a_r;
        uint4 av = make_uint4(0, 0, 0, 0);
        if (gr < M) av = *(const uint4*)&A[(size_t)gr * K + k0 + a_k8];
        *(uint4*)&As[a_r * LD + a_k8] = av;
        if (tid < 128) {
            const int nr = tid >> 2, k8 = (tid & 3) * 8;
            *(uint4*)&Bs[nr * LD + k8] = *(const uint4*)&Bt[(size_t)nr * K + k0 + k8];
        }
        __syncthreads();
        const half8_t af = *(const half8_t*)&As[(w * 16 + l16) * LD + quad * 8];
        #pragma unroll
        for (int c = 0; c < 2; ++c) {
            const half8_t bf = *(const half8_t*)&Bs[(c * 16 + l16) * LD + quad * 8];
            acc[c] = __builtin_amdgcn_mfma_f32_16x16x32_f16(af, bf, acc[c], 0, 0, 0);
        }
        __syncthreads();
    }
    #pragma unroll
    for (int c = 0; c < 2; ++c) {
        #pragma unroll
        for (int r = 0; r < 4; ++r) {
            int row = bm + w * 16 + quad * 4 + r;
            if (row < M)
                out[(size_t)row * 32 + c * 16 + l16] =
                    acc[c][r] * 0.125f + bias[c * 16 + l16];
        }
    }
}

// ---------------------------------------------------------------------------
// Launch
// ---------------------------------------------------------------------------
extern "C" void kernel_launch(void* const* d_in, const int* in_sizes, int n_in,
                              void* d_out, int out_size, void* d_ws, size_t ws_size,
                              hipStream_t stream) {
    const float* x   = (const float*)d_in[0];
    const int*   ei  = (const int*)d_in[1];
    const float* W1  = (const float*)d_in[2];
    const float* as1 = (const float*)d_in[3];
    const float* ad1 = (const float*)d_in[4];
    const float* b1  = (const float*)d_in[5];
    const float* W2  = (const float*)d_in[6];
    const float* as2 = (const float*)d_in[7];
    const float* ad2 = (const float*)d_in[8];
    const float* b2  = (const float*)d_in[9];

    const int n = N_NODES;
    const int e = E_EDGES;

    // ---- workspace layout (with lifetime-based aliasing) ----
    char* w = (char*)d_ws;
    __half* partial = (__half*)w; w += (size_t)n * 8 * 64 * 2;  // 20.48 MB
    __half* h_buf   = (__half*)w; w += (size_t)n * 512 * 2;     // 20.48 MB
    __half* y1h     = (__half*)w; w += (size_t)n * 64 * 2;      //  2.56 MB
    __half* W1t     = (__half*)w; w += (size_t)512 * 256 * 2;
    __half* W2f     = (__half*)w; w += (size_t)32 * 512 * 2;
    float*  uv      = (float*)w;  w += (size_t)16 * 64 * 4;
    float*  asrc    = (float*)w;  w += (size_t)n * 8 * 4;
    float*  adst    = (float*)w;  w += (size_t)n * 8 * 4;
    int* deg        = (int*)w; w += (size_t)n * 4;
    int* row_start  = (int*)w; w += (size_t)(n + 1) * 4;
    int* cursor     = (int*)w; w += (size_t)n * 4;
    int* csr_src    = (int*)w; w += (size_t)(e + n + 8) * 4;   // +pad for uint4 reads
    // aliases (sequential lifetimes):
    __half* xh    = partial;   // x fp16 [n][256]: dead once gemm1 done, before agg1 writes partial
    __half* S     = h_buf;     // [n][512] fp16: written after agg1 (last h_buf read)
    float* asrc2  = asrc;      // reused after agg1 (last asrc/adst read)
    float* adst2  = adst;

    // ---- CSR build (graph identical for both layers) ----
    init_deg_kernel<<<(n + 255) / 256, 256, 0, stream>>>(deg, n);
    count_deg_kernel<<<(e + 255) / 256, 256, 0, stream>>>(ei, e, deg);
    scan_kernel<<<1, 1024, 0, stream>>>(deg, row_start, cursor, n, e + n);
    scatter_kernel<<<(e + n + 255) / 256, 256, 0, stream>>>(ei, e, n, cursor, csr_src);

    // ---- fused x-cast + weight prep ----
    prep_kernel<<<(640000 + 148480) / 256, 256, 0, stream>>>(x, xh, W1, W2, as2, ad2,
                                                             W1t, W2f, uv);

    const int mb = (n + 127) / 128;  // 157

    // ---- Layer 1 ----
    gemm1_kernel<<<dim3(mb, 4), 256, 0, stream>>>(xh, W1t, h_buf, as1, ad1, asrc, adst, n);
    aggregate1_kernel<<<(n / 32) * 8, 256, 0, stream>>>(h_buf, asrc, adst, row_start,
                                                        csr_src, partial);
    merge1_kernel<<<n * 64 / 256, 256, 0, stream>>>(partial, b1, y1h);

    // ---- Layer 2: aggregate in y1-space, then one small GEMM ----
    logits2_kernel<<<n / 16, 256, 0, stream>>>(y1h, uv, asrc2, adst2);
    aggregate2_kernel<<<n / 4, 256, 0, stream>>>(y1h, asrc2, adst2, row_start, csr_src, S);
    gemm_out_kernel<<<(n + 63) / 64, 256, 0, stream>>>(S, W2f, b2, (float*)d_out, n);
}